// Round 1
// baseline (524.055 us; speedup 1.0000x reference)
//
#include <hip/hip_runtime.h>
#include <cstdint>

#define IND 128
#define HID 64
#define NEG_SLOPE 0.2f

// Order-preserving float<->uint mapping for atomicMax on floats.
// Encoded 0 (== memset 0) decodes below any real float => valid -inf sentinel,
// and every node has a self-loop so every m[] slot gets at least one update.
__device__ __forceinline__ unsigned enc_f(float f) {
  unsigned u = __float_as_uint(f);
  return (u & 0x80000000u) ? ~u : (u | 0x80000000u);
}
__device__ __forceinline__ float dec_f(unsigned u) {
  return __uint_as_float((u & 0x80000000u) ? (u & 0x7fffffffu) : ~u);
}

// ---------------------------------------------------------------------------
// K1: h = x @ W.T ; a_src = h @ att_src ; a_dst = h @ att_dst
// One wave handles 4 nodes; lane = hidden dim; W staged in LDS.
// ---------------------------------------------------------------------------
__global__ __launch_bounds__(256) void k_proj(
    const float* __restrict__ x, const float* __restrict__ W,
    const float* __restrict__ att_s, const float* __restrict__ att_d,
    float* __restrict__ h, float* __restrict__ a_src, float* __restrict__ a_dst,
    int n)
{
  __shared__ float Wl[HID * IND];
  for (int i = threadIdx.x; i < HID * IND; i += 256) Wl[i] = W[i];
  __syncthreads();

  const int lane = threadIdx.x & 63;
  const int wid  = threadIdx.x >> 6;
  const float as = att_s[lane];
  const float ad = att_d[lane];
  const float* wrow = &Wl[lane * IND];

  long long g  = (long long)blockIdx.x * 4 + wid;  // wave's 4-node group
  long long n0 = g * 4;
  if (n0 >= n) return;

  long long nidx[4];
#pragma unroll
  for (int j = 0; j < 4; ++j) {
    long long nj = n0 + j;
    nidx[j] = (nj < n) ? nj : (long long)(n - 1);   // clamp; writes guarded later
  }

  float acc[4] = {0.f, 0.f, 0.f, 0.f};
  for (int k = 0; k < IND; k += 4) {
    float4 wv = *(const float4*)(wrow + k);
#pragma unroll
    for (int j = 0; j < 4; ++j) {
      float4 xv = *(const float4*)(x + nidx[j] * IND + k);
      acc[j] = fmaf(wv.x, xv.x, acc[j]);
      acc[j] = fmaf(wv.y, xv.y, acc[j]);
      acc[j] = fmaf(wv.z, xv.z, acc[j]);
      acc[j] = fmaf(wv.w, xv.w, acc[j]);
    }
  }

#pragma unroll
  for (int j = 0; j < 4; ++j) {
    long long nj = n0 + j;
    if (nj >= n) break;
    h[nj * HID + lane] = acc[j];
    float sa = acc[j] * as;
    float sd = acc[j] * ad;
#pragma unroll
    for (int o = 32; o; o >>= 1) {
      sa += __shfl_xor(sa, o, 64);
      sd += __shfl_xor(sd, o, 64);
    }
    if (lane == 0) { a_src[nj] = sa; a_dst[nj] = sd; }
  }
}

// ---------------------------------------------------------------------------
// K2: e = leaky_relu(a_src[src] + a_dst[dst]); m[dst] = max(m[dst], e)
// Edges [0,E) are real; [E, E+n) are self-loops (src=dst=idx-E).
// ---------------------------------------------------------------------------
__global__ __launch_bounds__(256) void k_edge_score(
    const int* __restrict__ ei, const float* __restrict__ a_src,
    const float* __restrict__ a_dst, float* __restrict__ e_buf,
    unsigned* __restrict__ m_u, int E, int n)
{
  long long idx = (long long)blockIdx.x * 256 + threadIdx.x;
  long long E2 = (long long)E + n;
  if (idx >= E2) return;
  int s, d;
  if (idx < E) { s = ei[idx]; d = ei[E + idx]; }
  else         { s = d = (int)(idx - E); }
  float v = a_src[s] + a_dst[d];
  v = (v >= 0.f) ? v : NEG_SLOPE * v;
  e_buf[idx] = v;
  atomicMax(m_u + d, enc_f(v));
}

// ---------------------------------------------------------------------------
// K3: ex = exp(e - m[dst]); s[dst] += ex   (e_buf overwritten with ex)
// ---------------------------------------------------------------------------
__global__ __launch_bounds__(256) void k_edge_exp(
    const int* __restrict__ ei, float* __restrict__ e_buf,
    const unsigned* __restrict__ m_u, float* __restrict__ s_sum, int E, int n)
{
  long long idx = (long long)blockIdx.x * 256 + threadIdx.x;
  long long E2 = (long long)E + n;
  if (idx >= E2) return;
  int d = (idx < E) ? ei[E + idx] : (int)(idx - E);
  float m  = dec_f(m_u[d]);
  float ex = expf(e_buf[idx] - m);
  e_buf[idx] = ex;
  atomicAdd(s_sum + d, ex);
}

// ---------------------------------------------------------------------------
// K4: out_h[dst, :] += (ex/s[dst]) * h[src, :]
// Thread per (edge, dim); each wave covers exactly one edge (64 dims).
// ---------------------------------------------------------------------------
__global__ __launch_bounds__(256) void k_aggregate(
    const int* __restrict__ ei, const float* __restrict__ e_buf,
    const float* __restrict__ s_sum, const float* __restrict__ h,
    float* __restrict__ out_h, int E, int n)
{
  long long t  = (long long)blockIdx.x * 256 + threadIdx.x;
  long long E2 = (long long)E + n;
  if (t >= E2 * HID) return;
  int e  = (int)(t >> 6);
  int dd = (int)(t & 63);
  int src, dst;
  if (e < E) { src = ei[e]; dst = ei[E + e]; }
  else       { src = dst = e - E; }
  float alpha = e_buf[e] / s_sum[dst];
  atomicAdd(out_h + (long long)dst * HID + dd, alpha * h[(long long)src * HID + dd]);
}

// ---------------------------------------------------------------------------
// K5: y = sigmoid(relu(out_h + bias) @ W_lin.T + b_lin)
// Wave per node, lane = hidden dim, shfl reduction for the final dot.
// ---------------------------------------------------------------------------
__global__ __launch_bounds__(256) void k_final(
    const float* __restrict__ out_h, const float* __restrict__ bias,
    const float* __restrict__ W_lin, const float* __restrict__ b_lin,
    float* __restrict__ y, int n)
{
  int lane = threadIdx.x & 63;
  int wid  = threadIdx.x >> 6;
  long long node = (long long)blockIdx.x * 4 + wid;
  if (node >= n) return;
  float v = out_h[node * HID + lane] + bias[lane];
  v = fmaxf(v, 0.f);
  float z = v * W_lin[lane];
#pragma unroll
  for (int o = 32; o; o >>= 1) z += __shfl_xor(z, o, 64);
  if (lane == 0) {
    z += b_lin[0];
    y[node] = 1.f / (1.f + expf(-z));
  }
}

// ---------------------------------------------------------------------------

extern "C" void kernel_launch(void* const* d_in, const int* in_sizes, int n_in,
                              void* d_out, int out_size, void* d_ws, size_t ws_size,
                              hipStream_t stream)
{
  const float* x     = (const float*)d_in[0];
  const int*   ei    = (const int*)d_in[1];    // [2, E] row-major: row0=src, row1=dst
  const float* W     = (const float*)d_in[2];
  const float* att_s = (const float*)d_in[3];
  const float* att_d = (const float*)d_in[4];
  const float* bias  = (const float*)d_in[5];
  const float* W_lin = (const float*)d_in[6];
  const float* b_lin = (const float*)d_in[7];
  float* y = (float*)d_out;

  const int n = in_sizes[0] / IND;
  const int E = in_sizes[1] / 2;
  const long long E2 = (long long)E + n;

  // Workspace carve-up (~30 MB total)
  char* ws = (char*)d_ws;
  float*    h     = (float*)ws;    ws += (size_t)n * HID * sizeof(float);
  float*    e_buf = (float*)ws;    ws += (size_t)E2 * sizeof(float);
  float*    a_src = (float*)ws;    ws += (size_t)n * sizeof(float);
  float*    a_dst = (float*)ws;    ws += (size_t)n * sizeof(float);
  unsigned* m_u   = (unsigned*)ws; ws += (size_t)n * sizeof(unsigned);
  float*    s_sum = (float*)ws;    ws += (size_t)n * sizeof(float);
  float*    out_h = (float*)ws;    ws += (size_t)n * HID * sizeof(float);

  // d_ws is re-poisoned to 0xAA before every launch -> must re-init each call.
  hipMemsetAsync(m_u,   0, (size_t)n * sizeof(unsigned), stream);
  hipMemsetAsync(s_sum, 0, (size_t)n * sizeof(float), stream);
  hipMemsetAsync(out_h, 0, (size_t)n * HID * sizeof(float), stream);

  const int groups  = (n + 3) / 4;        // 4 nodes per wave
  const int blocks1 = (groups + 3) / 4;   // 4 waves per block
  k_proj<<<blocks1, 256, 0, stream>>>(x, W, att_s, att_d, h, a_src, a_dst, n);

  const int blocksE = (int)((E2 + 255) / 256);
  k_edge_score<<<blocksE, 256, 0, stream>>>(ei, a_src, a_dst, e_buf, m_u, E, n);
  k_edge_exp<<<blocksE, 256, 0, stream>>>(ei, e_buf, m_u, s_sum, E, n);

  const long long tot = E2 * HID;
  const int blocksA = (int)((tot + 255) / 256);
  k_aggregate<<<blocksA, 256, 0, stream>>>(ei, e_buf, s_sum, h, out_h, E, n);

  const int blocksF = (n + 3) / 4;
  k_final<<<blocksF, 256, 0, stream>>>(out_h, bias, W_lin, b_lin, y, n);
}

// Round 2
// 496.121 us; speedup vs baseline: 1.0563x; 1.0563x over previous
//
#include <hip/hip_runtime.h>
#include <cstdint>

#define IND 128
#define HID 64
#define NEG_SLOPE 0.2f

// ---------------------------------------------------------------------------
// K1: h = x @ W.T ; a_src = h @ att_src ; a_dst = h @ att_dst
// One wave handles 4 nodes; lane = hidden dim; W staged in LDS.
// ---------------------------------------------------------------------------
__global__ __launch_bounds__(256) void k_proj(
    const float* __restrict__ x, const float* __restrict__ W,
    const float* __restrict__ att_s, const float* __restrict__ att_d,
    float* __restrict__ h, float* __restrict__ a_src, float* __restrict__ a_dst,
    int n)
{
  __shared__ float Wl[HID * IND];
  for (int i = threadIdx.x; i < HID * IND; i += 256) Wl[i] = W[i];
  __syncthreads();

  const int lane = threadIdx.x & 63;
  const int wid  = threadIdx.x >> 6;
  const float as = att_s[lane];
  const float ad = att_d[lane];
  const float* wrow = &Wl[lane * IND];

  long long g  = (long long)blockIdx.x * 4 + wid;
  long long n0 = g * 4;
  if (n0 >= n) return;

  long long nidx[4];
#pragma unroll
  for (int j = 0; j < 4; ++j) {
    long long nj = n0 + j;
    nidx[j] = (nj < n) ? nj : (long long)(n - 1);
  }

  float acc[4] = {0.f, 0.f, 0.f, 0.f};
  for (int k = 0; k < IND; k += 4) {
    float4 wv = *(const float4*)(wrow + k);
#pragma unroll
    for (int j = 0; j < 4; ++j) {
      float4 xv = *(const float4*)(x + nidx[j] * IND + k);
      acc[j] = fmaf(wv.x, xv.x, acc[j]);
      acc[j] = fmaf(wv.y, xv.y, acc[j]);
      acc[j] = fmaf(wv.z, xv.z, acc[j]);
      acc[j] = fmaf(wv.w, xv.w, acc[j]);
    }
  }

#pragma unroll
  for (int j = 0; j < 4; ++j) {
    long long nj = n0 + j;
    if (nj >= n) break;
    h[nj * HID + lane] = acc[j];
    float sa = acc[j] * as;
    float sd = acc[j] * ad;
#pragma unroll
    for (int o = 32; o; o >>= 1) {
      sa += __shfl_xor(sa, o, 64);
      sd += __shfl_xor(sd, o, 64);
    }
    if (lane == 0) { a_src[nj] = sa; a_dst[nj] = sd; }
  }
}

// ---------------------------------------------------------------------------
// K2: histogram of real-edge in-degrees. deg[] memset to 0 beforehand;
// self-loop (+1) is folded in arithmetically downstream.
// ---------------------------------------------------------------------------
__global__ __launch_bounds__(256) void k_hist(
    const int* __restrict__ ei, int* __restrict__ deg, int E)
{
  long long idx = (long long)blockIdx.x * 256 + threadIdx.x;
  if (idx >= E) return;
  atomicAdd(deg + ei[E + idx], 1);
}

// ---------------------------------------------------------------------------
// K3: exclusive prefix scan of (deg[i]+1) -> row_start, cursor. Single block.
// Thread t owns a contiguous chunk; serial sum, block scan, serial write-out.
// ---------------------------------------------------------------------------
__global__ __launch_bounds__(256) void k_scan(
    const int* __restrict__ deg, int* __restrict__ row_start,
    int* __restrict__ cursor, int n)
{
  __shared__ int sums[256];
  const int tid = threadIdx.x;
  const int chunk = (n + 255) / 256;
  const int lo = tid * chunk;
  const int hi = (lo + chunk < n) ? lo + chunk : n;

  int s = 0;
  for (int i = lo; i < hi; ++i) s += deg[i] + 1;
  sums[tid] = s;
  __syncthreads();
  for (int off = 1; off < 256; off <<= 1) {
    int t = (tid >= off) ? sums[tid - off] : 0;
    __syncthreads();
    sums[tid] += t;
    __syncthreads();
  }
  int run = sums[tid] - s;   // exclusive prefix of this thread's chunk
  for (int i = lo; i < hi; ++i) {
    row_start[i] = run;
    cursor[i]    = run;
    run += deg[i] + 1;
  }
}

// ---------------------------------------------------------------------------
// K4: scatter edges into CSR order, with leaky-relu score computed inline.
// idx in [0,E) are real edges; [E, E+n) are self-loops.
// ---------------------------------------------------------------------------
__global__ __launch_bounds__(256) void k_scatter(
    const int* __restrict__ ei, const float* __restrict__ a_src,
    const float* __restrict__ a_dst, int* __restrict__ cursor,
    int* __restrict__ csr_src, float* __restrict__ csr_sc, int E, int n)
{
  long long idx = (long long)blockIdx.x * 256 + threadIdx.x;
  long long E2 = (long long)E + n;
  if (idx >= E2) return;
  int s, d;
  if (idx < E) { s = ei[idx]; d = ei[E + idx]; }
  else         { s = d = (int)(idx - E); }
  float v = a_src[s] + a_dst[d];
  v = (v >= 0.f) ? v : NEG_SLOPE * v;
  int pos = atomicAdd(cursor + d, 1);
  csr_src[pos] = s;
  csr_sc[pos]  = v;
}

// ---------------------------------------------------------------------------
// K5: fused per-node softmax + gather-aggregate + relu + W_lin dot + sigmoid.
// One wave per destination node; lane = hidden dim for the aggregation.
// No atomics: each node's result is private to its wave.
// ---------------------------------------------------------------------------
__global__ __launch_bounds__(256) void k_gather_final(
    const int* __restrict__ row_start, const int* __restrict__ deg,
    const int* __restrict__ csr_src, const float* __restrict__ csr_sc,
    const float* __restrict__ h, const float* __restrict__ bias,
    const float* __restrict__ W_lin, const float* __restrict__ b_lin,
    float* __restrict__ y, int n)
{
  __shared__ int   sh_src[4][64];
  __shared__ float sh_w[4][64];

  const int lane = threadIdx.x & 63;
  const int wid  = threadIdx.x >> 6;
  const int node = blockIdx.x * 4 + wid;
  if (node >= n) return;

  const int rs = row_start[node];
  const int dg = deg[node] + 1;          // + self-loop

  // --- pass 1: max over this node's edge scores (lanes parallel over edges)
  float m = -INFINITY;
  for (int b = 0; b < dg; b += 64) {
    float v = (b + lane < dg) ? csr_sc[rs + b + lane] : -INFINITY;
    m = fmaxf(m, v);
  }
#pragma unroll
  for (int o = 32; o; o >>= 1) m = fmaxf(m, __shfl_xor(m, o, 64));

  // --- pass 2: sum of exp
  float ssum = 0.f;
  for (int b = 0; b < dg; b += 64) {
    if (b + lane < dg) ssum += expf(csr_sc[rs + b + lane] - m);
  }
#pragma unroll
  for (int o = 32; o; o >>= 1) ssum += __shfl_xor(ssum, o, 64);
  const float inv = 1.f / ssum;

  // --- pass 3: acc[lane] = sum_e alpha_e * h[src_e][lane]
  float acc = 0.f;
  for (int b = 0; b < dg; b += 64) {
    const int rem = dg - b;
    const int cnt = rem < 64 ? rem : 64;
    if (lane < cnt) {
      sh_src[wid][lane] = csr_src[rs + b + lane];
      sh_w[wid][lane]   = expf(csr_sc[rs + b + lane] - m) * inv;
    }
    __builtin_amdgcn_wave_barrier();   // same-wave LDS RAW; compiler-order only
    for (int j = 0; j < cnt; ++j) {
      const int   sj = sh_src[wid][j];   // LDS broadcast read
      const float wj = sh_w[wid][j];
      acc = fmaf(wj, h[(long long)sj * HID + lane], acc);
    }
    __builtin_amdgcn_wave_barrier();
  }

  // --- epilogue: relu -> dot W_lin -> sigmoid
  float v = fmaxf(acc + bias[lane], 0.f);
  float z = v * W_lin[lane];
#pragma unroll
  for (int o = 32; o; o >>= 1) z += __shfl_xor(z, o, 64);
  if (lane == 0) {
    z += b_lin[0];
    y[node] = 1.f / (1.f + expf(-z));
  }
}

// ---------------------------------------------------------------------------

extern "C" void kernel_launch(void* const* d_in, const int* in_sizes, int n_in,
                              void* d_out, int out_size, void* d_ws, size_t ws_size,
                              hipStream_t stream)
{
  const float* x     = (const float*)d_in[0];
  const int*   ei    = (const int*)d_in[1];    // [2, E]: row0=src, row1=dst
  const float* W     = (const float*)d_in[2];
  const float* att_s = (const float*)d_in[3];
  const float* att_d = (const float*)d_in[4];
  const float* bias  = (const float*)d_in[5];
  const float* W_lin = (const float*)d_in[6];
  const float* b_lin = (const float*)d_in[7];
  float* y = (float*)d_out;

  const int n = in_sizes[0] / IND;
  const int E = in_sizes[1] / 2;
  const long long E2 = (long long)E + n;

  // Workspace carve-up (~20.6 MB)
  char* ws = (char*)d_ws;
  float* h        = (float*)ws; ws += (size_t)n * HID * sizeof(float);
  float* a_src    = (float*)ws; ws += (size_t)n * sizeof(float);
  float* a_dst    = (float*)ws; ws += (size_t)n * sizeof(float);
  int*   deg      = (int*)ws;   ws += (size_t)n * sizeof(int);
  int*   row_st   = (int*)ws;   ws += (size_t)n * sizeof(int);
  int*   cursor   = (int*)ws;   ws += (size_t)n * sizeof(int);
  int*   csr_src  = (int*)ws;   ws += (size_t)E2 * sizeof(int);
  float* csr_sc   = (float*)ws; ws += (size_t)E2 * sizeof(float);

  // d_ws re-poisoned to 0xAA every launch -> re-init each call.
  hipMemsetAsync(deg, 0, (size_t)n * sizeof(int), stream);

  k_hist<<<(E + 255) / 256, 256, 0, stream>>>(ei, deg, E);
  k_scan<<<1, 256, 0, stream>>>(deg, row_st, cursor, n);

  const int groups  = (n + 3) / 4;
  const int blocks1 = (groups + 3) / 4;
  k_proj<<<blocks1, 256, 0, stream>>>(x, W, att_s, att_d, h, a_src, a_dst, n);

  k_scatter<<<(int)((E2 + 255) / 256), 256, 0, stream>>>(
      ei, a_src, a_dst, cursor, csr_src, csr_sc, E, n);

  k_gather_final<<<(n + 3) / 4, 256, 0, stream>>>(
      row_st, deg, csr_src, csr_sc, h, bias, W_lin, b_lin, y, n);
}

// Round 3
// 489.230 us; speedup vs baseline: 1.0712x; 1.0141x over previous
//
#include <hip/hip_runtime.h>
#include <cstdint>

#define IND 128
#define HID 64
#define NEG_SLOPE 0.2f

// ---------------------------------------------------------------------------
// K1: h = x @ W.T ; a_src = h @ att_src ; a_dst = h @ att_dst
// Lane = hidden dim. One wave handles 8 nodes. W transposed in LDS with
// stride 65 (bank = (k+lane)%32 -> conflict-free; 2-way lane alias is free).
// x-row addresses are wave-uniform (readfirstlane) -> scalar loads.
// ---------------------------------------------------------------------------
__global__ __launch_bounds__(256) void k_proj(
    const float* __restrict__ x, const float* __restrict__ W,
    const float* __restrict__ att_s, const float* __restrict__ att_d,
    float* __restrict__ h, float* __restrict__ a_src, float* __restrict__ a_dst,
    int n)
{
  __shared__ float Wt[IND * 65];   // Wt[k*65 + hid] = W[hid*128 + k]
  for (int i = threadIdx.x; i < HID * IND; i += 256) {
    int hid = i >> 7;        // i / 128
    int k   = i & 127;
    Wt[k * 65 + hid] = W[i]; // consecutive tid -> consecutive k -> conflict-free
  }
  __syncthreads();

  const int lane = threadIdx.x & 63;
  const int wid  = threadIdx.x >> 6;
  const float as = att_s[lane];
  const float ad = att_d[lane];

  // wave-uniform first node of this wave's 8-node group
  const int n0 = __builtin_amdgcn_readfirstlane((blockIdx.x * 4 + wid) * 8);
  if (n0 >= n) return;

  int nidx[8];
#pragma unroll
  for (int j = 0; j < 8; ++j) {
    int nj = n0 + j;
    nidx[j] = (nj < n) ? nj : (n - 1);   // clamp; stores guarded below
  }

  float acc[8] = {0.f, 0.f, 0.f, 0.f, 0.f, 0.f, 0.f, 0.f};

  for (int kc = 0; kc < IND; kc += 16) {
    float wv[16];
#pragma unroll
    for (int i = 0; i < 16; ++i) wv[i] = Wt[(kc + i) * 65 + lane];
#pragma unroll
    for (int j = 0; j < 8; ++j) {
      const float4* xp = (const float4*)(x + (size_t)nidx[j] * IND + kc);
#pragma unroll
      for (int q = 0; q < 4; ++q) {
        float4 xv = xp[q];              // wave-uniform address -> broadcast
        acc[j] = fmaf(wv[q * 4 + 0], xv.x, acc[j]);
        acc[j] = fmaf(wv[q * 4 + 1], xv.y, acc[j]);
        acc[j] = fmaf(wv[q * 4 + 2], xv.z, acc[j]);
        acc[j] = fmaf(wv[q * 4 + 3], xv.w, acc[j]);
      }
    }
  }

#pragma unroll
  for (int j = 0; j < 8; ++j) {
    int nj = n0 + j;
    if (nj >= n) break;
    h[(size_t)nj * HID + lane] = acc[j];
    float sa = acc[j] * as;
    float sd = acc[j] * ad;
#pragma unroll
    for (int o = 32; o; o >>= 1) {
      sa += __shfl_xor(sa, o, 64);
      sd += __shfl_xor(sd, o, 64);
    }
    if (lane == 0) { a_src[nj] = sa; a_dst[nj] = sd; }
  }
}

// ---------------------------------------------------------------------------
// K2: histogram of real-edge in-degrees (deg[] pre-zeroed; self-loop +1 folded
// in arithmetically downstream).
// ---------------------------------------------------------------------------
__global__ __launch_bounds__(256) void k_hist(
    const int* __restrict__ ei, int* __restrict__ deg, int E)
{
  long long idx = (long long)blockIdx.x * 256 + threadIdx.x;
  if (idx >= E) return;
  atomicAdd(deg + ei[E + idx], 1);
}

// ---------------------------------------------------------------------------
// K3: exclusive scan of (deg[i]+1) -> row_start, cursor. Single 1024-block.
// ---------------------------------------------------------------------------
__global__ __launch_bounds__(1024) void k_scan(
    const int* __restrict__ deg, int* __restrict__ row_start,
    int* __restrict__ cursor, int n)
{
  __shared__ int sums[1024];
  const int tid = threadIdx.x;
  const int chunk = (n + 1023) >> 10;
  const int lo = tid * chunk;
  const int hi = (lo + chunk < n) ? lo + chunk : n;

  int s = 0;
  for (int i = lo; i < hi; ++i) s += deg[i] + 1;
  sums[tid] = s;
  __syncthreads();
  for (int off = 1; off < 1024; off <<= 1) {
    int t = (tid >= off) ? sums[tid - off] : 0;
    __syncthreads();
    sums[tid] += t;
    __syncthreads();
  }
  int run = sums[tid] - s;
  for (int i = lo; i < hi; ++i) {
    row_start[i] = run;
    cursor[i]    = run;
    run += deg[i] + 1;
  }
}

// ---------------------------------------------------------------------------
// K4: scatter edges into CSR, packed {src, w=exp(leaky_relu(score))} 8B.
// No max-shift: |score| <~ 10 so exp() is safe in fp32, and the softmax ratio
// is mathematically identical.
// ---------------------------------------------------------------------------
__global__ __launch_bounds__(256) void k_scatter(
    const int* __restrict__ ei, const float* __restrict__ a_src,
    const float* __restrict__ a_dst, int* __restrict__ cursor,
    float2* __restrict__ csr, int E, int n)
{
  long long idx = (long long)blockIdx.x * 256 + threadIdx.x;
  long long E2 = (long long)E + n;
  if (idx >= E2) return;
  int s, d;
  if (idx < E) { s = ei[idx]; d = ei[E + idx]; }
  else         { s = d = (int)(idx - E); }
  float v = a_src[s] + a_dst[d];
  v = (v >= 0.f) ? v : NEG_SLOPE * v;
  float w = expf(v);
  int pos = atomicAdd(cursor + d, 1);
  csr[pos] = make_float2(__int_as_float(s), w);
}

// ---------------------------------------------------------------------------
// K5: per-node softmax-normalize + gather-aggregate + relu + W_lin + sigmoid.
// One wave per node; lane = hidden dim; shfl broadcast of (src, w); 4x-unrolled
// independent h-row loads for latency pipelining. No atomics, no LDS.
// ---------------------------------------------------------------------------
__global__ __launch_bounds__(256) void k_gather_final(
    const int* __restrict__ row_start, const int* __restrict__ deg,
    const float2* __restrict__ csr, const float* __restrict__ h,
    const float* __restrict__ bias, const float* __restrict__ W_lin,
    const float* __restrict__ b_lin, float* __restrict__ y, int n)
{
  const int lane = threadIdx.x & 63;
  const int wid  = threadIdx.x >> 6;
  const int node = blockIdx.x * 4 + wid;
  if (node >= n) return;

  const int rs = row_start[node];
  const int dg = deg[node] + 1;          // + self-loop

  // --- pass 1: sum of exp-weights
  float part = 0.f;
  for (int b = 0; b < dg; b += 64) {
    int i = b + lane;
    if (i < dg) part += csr[rs + i].y;
  }
  float ssum = part;
#pragma unroll
  for (int o = 32; o; o >>= 1) ssum += __shfl_xor(ssum, o, 64);
  const float inv = 1.f / ssum;

  // --- pass 2: acc[lane] = sum_e (w_e*inv) * h[src_e][lane]
  float acc = 0.f;
  for (int b = 0; b < dg; b += 64) {
    int i = b + lane;
    float2 pk = (i < dg) ? csr[rs + i] : make_float2(0.f, 0.f);
    int   srcl = __float_as_int(pk.x);
    float wl   = pk.y * inv;
    const int cnt = (dg - b < 64) ? dg - b : 64;

    int j = 0;
    for (; j + 4 <= cnt; j += 4) {
      int   s0 = __shfl(srcl, j,     64), s1 = __shfl(srcl, j + 1, 64);
      int   s2 = __shfl(srcl, j + 2, 64), s3 = __shfl(srcl, j + 3, 64);
      float w0 = __shfl(wl,   j,     64), w1 = __shfl(wl,   j + 1, 64);
      float w2 = __shfl(wl,   j + 2, 64), w3 = __shfl(wl,   j + 3, 64);
      float h0 = h[(size_t)s0 * HID + lane];
      float h1 = h[(size_t)s1 * HID + lane];
      float h2 = h[(size_t)s2 * HID + lane];
      float h3 = h[(size_t)s3 * HID + lane];
      acc = fmaf(w0, h0, acc);
      acc = fmaf(w1, h1, acc);
      acc = fmaf(w2, h2, acc);
      acc = fmaf(w3, h3, acc);
    }
    for (; j < cnt; ++j) {
      int   sj = __shfl(srcl, j, 64);
      float wj = __shfl(wl,   j, 64);
      acc = fmaf(wj, h[(size_t)sj * HID + lane], acc);
    }
  }

  // --- epilogue: relu -> dot W_lin -> sigmoid
  float v = fmaxf(acc + bias[lane], 0.f);
  float z = v * W_lin[lane];
#pragma unroll
  for (int o = 32; o; o >>= 1) z += __shfl_xor(z, o, 64);
  if (lane == 0) {
    z += b_lin[0];
    y[node] = 1.f / (1.f + expf(-z));
  }
}

// ---------------------------------------------------------------------------

extern "C" void kernel_launch(void* const* d_in, const int* in_sizes, int n_in,
                              void* d_out, int out_size, void* d_ws, size_t ws_size,
                              hipStream_t stream)
{
  const float* x     = (const float*)d_in[0];
  const int*   ei    = (const int*)d_in[1];    // [2, E]: row0=src, row1=dst
  const float* W     = (const float*)d_in[2];
  const float* att_s = (const float*)d_in[3];
  const float* att_d = (const float*)d_in[4];
  const float* bias  = (const float*)d_in[5];
  const float* W_lin = (const float*)d_in[6];
  const float* b_lin = (const float*)d_in[7];
  float* y = (float*)d_out;

  const int n = in_sizes[0] / IND;
  const int E = in_sizes[1] / 2;
  const long long E2 = (long long)E + n;

  // Workspace carve-up (~20.5 MB)
  char* ws = (char*)d_ws;
  float*  h      = (float*)ws;  ws += (size_t)n * HID * sizeof(float);
  float*  a_src  = (float*)ws;  ws += (size_t)n * sizeof(float);
  float*  a_dst  = (float*)ws;  ws += (size_t)n * sizeof(float);
  int*    deg    = (int*)ws;    ws += (size_t)n * sizeof(int);
  int*    row_st = (int*)ws;    ws += (size_t)n * sizeof(int);
  int*    cursor = (int*)ws;    ws += (size_t)n * sizeof(int);
  float2* csr    = (float2*)ws; ws += (size_t)E2 * sizeof(float2);

  // d_ws re-poisoned to 0xAA every launch -> re-init each call.
  hipMemsetAsync(deg, 0, (size_t)n * sizeof(int), stream);

  k_hist<<<(E + 255) / 256, 256, 0, stream>>>(ei, deg, E);
  k_scan<<<1, 1024, 0, stream>>>(deg, row_st, cursor, n);

  const int waves1  = (n + 7) / 8;
  const int blocks1 = (waves1 + 3) / 4;
  k_proj<<<blocks1, 256, 0, stream>>>(x, W, att_s, att_d, h, a_src, a_dst, n);

  k_scatter<<<(int)((E2 + 255) / 256), 256, 0, stream>>>(
      ei, a_src, a_dst, cursor, csr, E, n);

  k_gather_final<<<(n + 3) / 4, 256, 0, stream>>>(
      row_st, deg, csr, h, bias, W_lin, b_lin, y, n);
}

// Round 4
// 330.336 us; speedup vs baseline: 1.5864x; 1.4810x over previous
//
#include <hip/hip_runtime.h>
#include <cstdint>

#define IND 128
#define HID 64
#define NEG_SLOPE 0.2f
#define LSTRIDE 132   // 128 + 4: 16B-aligned rows, (stride*4) % 32 banks == 16

// ---------------------------------------------------------------------------
// K1: h = x @ W.T ; a_src = h @ att_src ; a_dst = h @ att_dst
// Tiled GEMM: block = 64 nodes x 64 hid x K=128. x,W staged in LDS row-major
// (stride 132), thread microtile 4x4, k stepped by 4 (float4 fragments).
// a_src/a_dst fused via shfl + LDS atomic reduction.
// ---------------------------------------------------------------------------
__global__ __launch_bounds__(256) void k_proj(
    const float* __restrict__ x, const float* __restrict__ W,
    const float* __restrict__ att_s, const float* __restrict__ att_d,
    float* __restrict__ h, float* __restrict__ a_src, float* __restrict__ a_dst,
    int n)
{
  __shared__ float xs[64 * LSTRIDE];
  __shared__ float wt[64 * LSTRIDE];
  __shared__ float sa_l[64], sd_l[64];

  const int tid = threadIdx.x;
  const int nodeBase = blockIdx.x * 64;

  if (tid < 64) { sa_l[tid] = 0.f; sd_l[tid] = 0.f; }

  // stage W[hid][k] -> wt[hid*132 + k]: coalesced global float4, dense b128 LDS
#pragma unroll
  for (int it = 0; it < 8; ++it) {
    int fi = (it * 256 + tid) * 4;        // flat float idx into W (8192 total)
    int hid = fi >> 7, k = fi & 127;
    float4 v = *(const float4*)(W + fi);
    *(float4*)&wt[hid * LSTRIDE + k] = v;
  }
  // stage 64 x rows (clamped at the tail; stores are guarded later)
#pragma unroll
  for (int it = 0; it < 8; ++it) {
    int fi = (it * 256 + tid) * 4;
    int nl = fi >> 7, k = fi & 127;
    int node = nodeBase + nl; if (node >= n) node = n - 1;
    float4 v = *(const float4*)(x + (size_t)node * IND + k);
    *(float4*)&xs[nl * LSTRIDE + k] = v;
  }
  __syncthreads();

  const int ng = tid & 15;   // node group: nodes 4*ng .. 4*ng+3 (block-local)
  const int hg = tid >> 4;   // hid  group: hids  4*hg .. 4*hg+3
  const float* xrow0 = &xs[(4 * ng) * LSTRIDE];
  const float* wrow0 = &wt[(4 * hg) * LSTRIDE];

  float acc[4][4];
#pragma unroll
  for (int j = 0; j < 4; ++j)
#pragma unroll
    for (int i = 0; i < 4; ++i) acc[j][i] = 0.f;

  for (int k = 0; k < IND; k += 4) {
    float4 a[4], b[4];
#pragma unroll
    for (int j = 0; j < 4; ++j) a[j] = *(const float4*)(xrow0 + j * LSTRIDE + k);
#pragma unroll
    for (int i = 0; i < 4; ++i) b[i] = *(const float4*)(wrow0 + i * LSTRIDE + k);
#pragma unroll
    for (int j = 0; j < 4; ++j)
#pragma unroll
      for (int i = 0; i < 4; ++i) {
        acc[j][i] = fmaf(a[j].x, b[i].x, acc[j][i]);
        acc[j][i] = fmaf(a[j].y, b[i].y, acc[j][i]);
        acc[j][i] = fmaf(a[j].z, b[i].z, acc[j][i]);
        acc[j][i] = fmaf(a[j].w, b[i].w, acc[j][i]);
      }
  }

  // store h tile: float4 per (node, 4 hids)
#pragma unroll
  for (int j = 0; j < 4; ++j) {
    int node = nodeBase + 4 * ng + j;
    if (node < n)
      *(float4*)(h + (size_t)node * HID + 4 * hg) =
          make_float4(acc[j][0], acc[j][1], acc[j][2], acc[j][3]);
  }

  // fused a_src/a_dst: partial dot over this thread's 4 hids, reduce over hg
  float4 as4 = *(const float4*)(att_s + 4 * hg);
  float4 ad4 = *(const float4*)(att_d + 4 * hg);
#pragma unroll
  for (int j = 0; j < 4; ++j) {
    float ps = acc[j][0]*as4.x + acc[j][1]*as4.y + acc[j][2]*as4.z + acc[j][3]*as4.w;
    float pd = acc[j][0]*ad4.x + acc[j][1]*ad4.y + acc[j][2]*ad4.z + acc[j][3]*ad4.w;
    ps += __shfl_xor(ps, 16, 64); ps += __shfl_xor(ps, 32, 64);
    pd += __shfl_xor(pd, 16, 64); pd += __shfl_xor(pd, 32, 64);
    if ((tid & 63) < 16) {       // one lane per (wave, node): cross-wave via LDS
      atomicAdd(&sa_l[4 * ng + j], ps);
      atomicAdd(&sd_l[4 * ng + j], pd);
    }
  }
  __syncthreads();
  if (tid < 64) {
    int node = nodeBase + tid;
    if (node < n) { a_src[node] = sa_l[tid]; a_dst[node] = sd_l[tid]; }
  }
}

// ---------------------------------------------------------------------------
// K2: histogram of real-edge in-degrees (deg[] pre-zeroed; self-loop +1 folded
// in arithmetically downstream).
// ---------------------------------------------------------------------------
__global__ __launch_bounds__(256) void k_hist(
    const int* __restrict__ ei, int* __restrict__ deg, int E)
{
  long long idx = (long long)blockIdx.x * 256 + threadIdx.x;
  if (idx >= E) return;
  atomicAdd(deg + ei[E + idx], 1);
}

// ---------------------------------------------------------------------------
// K3: exclusive scan of (deg[i]+1) -> row_start, cursor. Single 1024-block.
// ---------------------------------------------------------------------------
__global__ __launch_bounds__(1024) void k_scan(
    const int* __restrict__ deg, int* __restrict__ row_start,
    int* __restrict__ cursor, int n)
{
  __shared__ int sums[1024];
  const int tid = threadIdx.x;
  const int chunk = (n + 1023) >> 10;
  const int lo = tid * chunk;
  const int hi = (lo + chunk < n) ? lo + chunk : n;

  int s = 0;
  for (int i = lo; i < hi; ++i) s += deg[i] + 1;
  sums[tid] = s;
  __syncthreads();
  for (int off = 1; off < 1024; off <<= 1) {
    int t = (tid >= off) ? sums[tid - off] : 0;
    __syncthreads();
    sums[tid] += t;
    __syncthreads();
  }
  int run = sums[tid] - s;
  for (int i = lo; i < hi; ++i) {
    row_start[i] = run;
    cursor[i]    = run;
    run += deg[i] + 1;
  }
}

// ---------------------------------------------------------------------------
// K4: scatter edges into CSR, packed {src, w=exp(leaky_relu(score))} 8B.
// No max-shift: |score| <~ 10 so exp() is safe in fp32, and the softmax ratio
// is mathematically identical.
// ---------------------------------------------------------------------------
__global__ __launch_bounds__(256) void k_scatter(
    const int* __restrict__ ei, const float* __restrict__ a_src,
    const float* __restrict__ a_dst, int* __restrict__ cursor,
    float2* __restrict__ csr, int E, int n)
{
  long long idx = (long long)blockIdx.x * 256 + threadIdx.x;
  long long E2 = (long long)E + n;
  if (idx >= E2) return;
  int s, d;
  if (idx < E) { s = ei[idx]; d = ei[E + idx]; }
  else         { s = d = (int)(idx - E); }
  float v = a_src[s] + a_dst[d];
  v = (v >= 0.f) ? v : NEG_SLOPE * v;
  float w = expf(v);
  int pos = atomicAdd(cursor + d, 1);
  csr[pos] = make_float2(__int_as_float(s), w);
}

// ---------------------------------------------------------------------------
// K5: per-node softmax-normalize + gather-aggregate + relu + W_lin + sigmoid.
// One wave per node; lane = hidden dim; shfl broadcast of (src, w); 4x-unrolled
// independent h-row loads for latency pipelining. No atomics, no LDS.
// ---------------------------------------------------------------------------
__global__ __launch_bounds__(256) void k_gather_final(
    const int* __restrict__ row_start, const int* __restrict__ deg,
    const float2* __restrict__ csr, const float* __restrict__ h,
    const float* __restrict__ bias, const float* __restrict__ W_lin,
    const float* __restrict__ b_lin, float* __restrict__ y, int n)
{
  const int lane = threadIdx.x & 63;
  const int wid  = threadIdx.x >> 6;
  const int node = blockIdx.x * 4 + wid;
  if (node >= n) return;

  const int rs = row_start[node];
  const int dg = deg[node] + 1;          // + self-loop

  // --- pass 1: sum of exp-weights
  float part = 0.f;
  for (int b = 0; b < dg; b += 64) {
    int i = b + lane;
    if (i < dg) part += csr[rs + i].y;
  }
  float ssum = part;
#pragma unroll
  for (int o = 32; o; o >>= 1) ssum += __shfl_xor(ssum, o, 64);
  const float inv = 1.f / ssum;

  // --- pass 2: acc[lane] = sum_e (w_e*inv) * h[src_e][lane]
  float acc = 0.f;
  for (int b = 0; b < dg; b += 64) {
    int i = b + lane;
    float2 pk = (i < dg) ? csr[rs + i] : make_float2(0.f, 0.f);
    int   srcl = __float_as_int(pk.x);
    float wl   = pk.y * inv;
    const int cnt = (dg - b < 64) ? dg - b : 64;

    int j = 0;
    for (; j + 4 <= cnt; j += 4) {
      int   s0 = __shfl(srcl, j,     64), s1 = __shfl(srcl, j + 1, 64);
      int   s2 = __shfl(srcl, j + 2, 64), s3 = __shfl(srcl, j + 3, 64);
      float w0 = __shfl(wl,   j,     64), w1 = __shfl(wl,   j + 1, 64);
      float w2 = __shfl(wl,   j + 2, 64), w3 = __shfl(wl,   j + 3, 64);
      float h0 = h[(size_t)s0 * HID + lane];
      float h1 = h[(size_t)s1 * HID + lane];
      float h2 = h[(size_t)s2 * HID + lane];
      float h3 = h[(size_t)s3 * HID + lane];
      acc = fmaf(w0, h0, acc);
      acc = fmaf(w1, h1, acc);
      acc = fmaf(w2, h2, acc);
      acc = fmaf(w3, h3, acc);
    }
    for (; j < cnt; ++j) {
      int   sj = __shfl(srcl, j, 64);
      float wj = __shfl(wl,   j, 64);
      acc = fmaf(wj, h[(size_t)sj * HID + lane], acc);
    }
  }

  // --- epilogue: relu -> dot W_lin -> sigmoid
  float v = fmaxf(acc + bias[lane], 0.f);
  float z = v * W_lin[lane];
#pragma unroll
  for (int o = 32; o; o >>= 1) z += __shfl_xor(z, o, 64);
  if (lane == 0) {
    z += b_lin[0];
    y[node] = 1.f / (1.f + expf(-z));
  }
}

// ---------------------------------------------------------------------------

extern "C" void kernel_launch(void* const* d_in, const int* in_sizes, int n_in,
                              void* d_out, int out_size, void* d_ws, size_t ws_size,
                              hipStream_t stream)
{
  const float* x     = (const float*)d_in[0];
  const int*   ei    = (const int*)d_in[1];    // [2, E]: row0=src, row1=dst
  const float* W     = (const float*)d_in[2];
  const float* att_s = (const float*)d_in[3];
  const float* att_d = (const float*)d_in[4];
  const float* bias  = (const float*)d_in[5];
  const float* W_lin = (const float*)d_in[6];
  const float* b_lin = (const float*)d_in[7];
  float* y = (float*)d_out;

  const int n = in_sizes[0] / IND;
  const int E = in_sizes[1] / 2;
  const long long E2 = (long long)E + n;

  // Workspace carve-up (~20.5 MB)
  char* ws = (char*)d_ws;
  float*  h      = (float*)ws;  ws += (size_t)n * HID * sizeof(float);
  float*  a_src  = (float*)ws;  ws += (size_t)n * sizeof(float);
  float*  a_dst  = (float*)ws;  ws += (size_t)n * sizeof(float);
  int*    deg    = (int*)ws;    ws += (size_t)n * sizeof(int);
  int*    row_st = (int*)ws;    ws += (size_t)n * sizeof(int);
  int*    cursor = (int*)ws;    ws += (size_t)n * sizeof(int);
  float2* csr    = (float2*)ws; ws += (size_t)E2 * sizeof(float2);

  // d_ws re-poisoned to 0xAA every launch -> re-init each call.
  hipMemsetAsync(deg, 0, (size_t)n * sizeof(int), stream);

  k_hist<<<(E + 255) / 256, 256, 0, stream>>>(ei, deg, E);
  k_scan<<<1, 1024, 0, stream>>>(deg, row_st, cursor, n);

  k_proj<<<(n + 63) / 64, 256, 0, stream>>>(x, W, att_s, att_d, h, a_src, a_dst, n);

  k_scatter<<<(int)((E2 + 255) / 256), 256, 0, stream>>>(
      ei, a_src, a_dst, cursor, csr, E, n);

  k_gather_final<<<(n + 3) / 4, 256, 0, stream>>>(
      row_st, deg, csr, h, bias, W_lin, b_lin, y, n);
}

// Round 5
// 228.164 us; speedup vs baseline: 2.2968x; 1.4478x over previous
//
#include <hip/hip_runtime.h>
#include <cstdint>

#define IND 128
#define HID 64
#define NEG_SLOPE 0.2f
#define LSTRIDE 132   // 128 + 4: 16B-aligned rows, (stride*4) % 32 banks == 16

// ---------------------------------------------------------------------------
// K1: h = x @ W.T ; a_src = h @ att_src ; a_dst = h @ att_dst
// Tiled GEMM: block = 64 nodes x 64 hid x K=128. x,W staged in LDS row-major
// (stride 132), thread microtile 4x4, k stepped by 4 (float4 fragments).
// a_src/a_dst fused via shfl + LDS atomic reduction.
// ---------------------------------------------------------------------------
__global__ __launch_bounds__(256) void k_proj(
    const float* __restrict__ x, const float* __restrict__ W,
    const float* __restrict__ att_s, const float* __restrict__ att_d,
    float* __restrict__ h, float* __restrict__ a_src, float* __restrict__ a_dst,
    int n)
{
  __shared__ float xs[64 * LSTRIDE];
  __shared__ float wt[64 * LSTRIDE];
  __shared__ float sa_l[64], sd_l[64];

  const int tid = threadIdx.x;
  const int nodeBase = blockIdx.x * 64;

  if (tid < 64) { sa_l[tid] = 0.f; sd_l[tid] = 0.f; }

  // stage W[hid][k] -> wt[hid*132 + k]: coalesced global float4, dense b128 LDS
#pragma unroll
  for (int it = 0; it < 8; ++it) {
    int fi = (it * 256 + tid) * 4;        // flat float idx into W (8192 total)
    int hid = fi >> 7, k = fi & 127;
    float4 v = *(const float4*)(W + fi);
    *(float4*)&wt[hid * LSTRIDE + k] = v;
  }
  // stage 64 x rows (clamped at the tail; stores are guarded later)
#pragma unroll
  for (int it = 0; it < 8; ++it) {
    int fi = (it * 256 + tid) * 4;
    int nl = fi >> 7, k = fi & 127;
    int node = nodeBase + nl; if (node >= n) node = n - 1;
    float4 v = *(const float4*)(x + (size_t)node * IND + k);
    *(float4*)&xs[nl * LSTRIDE + k] = v;
  }
  __syncthreads();

  const int ng = tid & 15;   // node group: nodes 4*ng .. 4*ng+3 (block-local)
  const int hg = tid >> 4;   // hid  group: hids  4*hg .. 4*hg+3
  const float* xrow0 = &xs[(4 * ng) * LSTRIDE];
  const float* wrow0 = &wt[(4 * hg) * LSTRIDE];

  float acc[4][4];
#pragma unroll
  for (int j = 0; j < 4; ++j)
#pragma unroll
    for (int i = 0; i < 4; ++i) acc[j][i] = 0.f;

  for (int k = 0; k < IND; k += 4) {
    float4 a[4], b[4];
#pragma unroll
    for (int j = 0; j < 4; ++j) a[j] = *(const float4*)(xrow0 + j * LSTRIDE + k);
#pragma unroll
    for (int i = 0; i < 4; ++i) b[i] = *(const float4*)(wrow0 + i * LSTRIDE + k);
#pragma unroll
    for (int j = 0; j < 4; ++j)
#pragma unroll
      for (int i = 0; i < 4; ++i) {
        acc[j][i] = fmaf(a[j].x, b[i].x, acc[j][i]);
        acc[j][i] = fmaf(a[j].y, b[i].y, acc[j][i]);
        acc[j][i] = fmaf(a[j].z, b[i].z, acc[j][i]);
        acc[j][i] = fmaf(a[j].w, b[i].w, acc[j][i]);
      }
  }

  // store h tile: float4 per (node, 4 hids)
#pragma unroll
  for (int j = 0; j < 4; ++j) {
    int node = nodeBase + 4 * ng + j;
    if (node < n)
      *(float4*)(h + (size_t)node * HID + 4 * hg) =
          make_float4(acc[j][0], acc[j][1], acc[j][2], acc[j][3]);
  }

  // fused a_src/a_dst: partial dot over this thread's 4 hids, reduce over hg
  float4 as4 = *(const float4*)(att_s + 4 * hg);
  float4 ad4 = *(const float4*)(att_d + 4 * hg);
#pragma unroll
  for (int j = 0; j < 4; ++j) {
    float ps = acc[j][0]*as4.x + acc[j][1]*as4.y + acc[j][2]*as4.z + acc[j][3]*as4.w;
    float pd = acc[j][0]*ad4.x + acc[j][1]*ad4.y + acc[j][2]*ad4.z + acc[j][3]*ad4.w;
    ps += __shfl_xor(ps, 16, 64); ps += __shfl_xor(ps, 32, 64);
    pd += __shfl_xor(pd, 16, 64); pd += __shfl_xor(pd, 32, 64);
    if ((tid & 63) < 16) {       // one lane per (wave, node): cross-wave via LDS
      atomicAdd(&sa_l[4 * ng + j], ps);
      atomicAdd(&sd_l[4 * ng + j], pd);
    }
  }
  __syncthreads();
  if (tid < 64) {
    int node = nodeBase + tid;
    if (node < n) { a_src[node] = sa_l[tid]; a_dst[node] = sd_l[tid]; }
  }
}

// ---------------------------------------------------------------------------
// K2: histogram of real-edge in-degrees (deg[] pre-zeroed; self-loop +1 folded
// in arithmetically downstream).
// ---------------------------------------------------------------------------
__global__ __launch_bounds__(256) void k_hist(
    const int* __restrict__ ei, int* __restrict__ deg, int E)
{
  long long idx = (long long)blockIdx.x * 256 + threadIdx.x;
  if (idx >= E) return;
  atomicAdd(deg + ei[E + idx], 1);
}

// ---------------------------------------------------------------------------
// K3a: per-block partial sums of (deg[i]+1). 256 threads, 1 elem/thread.
// ---------------------------------------------------------------------------
__global__ __launch_bounds__(256) void k_scan_a(
    const int* __restrict__ deg, int* __restrict__ blockSums, int n)
{
  __shared__ int red[4];
  int i = blockIdx.x * 256 + threadIdx.x;
  int v = (i < n) ? deg[i] + 1 : 0;
#pragma unroll
  for (int o = 32; o; o >>= 1) v += __shfl_xor(v, o, 64);
  if ((threadIdx.x & 63) == 0) red[threadIdx.x >> 6] = v;
  __syncthreads();
  if (threadIdx.x == 0)
    blockSums[blockIdx.x] = red[0] + red[1] + red[2] + red[3];
}

// ---------------------------------------------------------------------------
// K3b: exclusive scan of blockSums in-place (nb <= 1024). Single block.
// ---------------------------------------------------------------------------
__global__ __launch_bounds__(1024) void k_scan_b(
    int* __restrict__ blockSums, int nb)
{
  __shared__ int sums[1024];
  const int tid = threadIdx.x;
  int v = (tid < nb) ? blockSums[tid] : 0;
  sums[tid] = v;
  __syncthreads();
  for (int off = 1; off < 1024; off <<= 1) {
    int t = (tid >= off) ? sums[tid - off] : 0;
    __syncthreads();
    sums[tid] += t;
    __syncthreads();
  }
  if (tid < nb) blockSums[tid] = sums[tid] - v;   // exclusive
}

// ---------------------------------------------------------------------------
// K3c: block-local exclusive scan + block offset -> row_start, cursor.
// ---------------------------------------------------------------------------
__global__ __launch_bounds__(256) void k_scan_c(
    const int* __restrict__ deg, const int* __restrict__ blockSums,
    int* __restrict__ row_start, int* __restrict__ cursor, int n)
{
  __shared__ int sums[256];
  const int tid = threadIdx.x;
  int i = blockIdx.x * 256 + tid;
  int v = (i < n) ? deg[i] + 1 : 0;
  sums[tid] = v;
  __syncthreads();
  for (int off = 1; off < 256; off <<= 1) {
    int t = (tid >= off) ? sums[tid - off] : 0;
    __syncthreads();
    sums[tid] += t;
    __syncthreads();
  }
  int ex = sums[tid] - v + blockSums[blockIdx.x];
  if (i < n) { row_start[i] = ex; cursor[i] = ex; }
}

// ---------------------------------------------------------------------------
// K4: scatter edges into CSR, packed {src, w=exp(leaky_relu(score))} 8B.
// No max-shift: |score| <~ 10 so exp() is safe in fp32, and the softmax ratio
// is mathematically identical.
// ---------------------------------------------------------------------------
__global__ __launch_bounds__(256) void k_scatter(
    const int* __restrict__ ei, const float* __restrict__ a_src,
    const float* __restrict__ a_dst, int* __restrict__ cursor,
    float2* __restrict__ csr, int E, int n)
{
  long long idx = (long long)blockIdx.x * 256 + threadIdx.x;
  long long E2 = (long long)E + n;
  if (idx >= E2) return;
  int s, d;
  if (idx < E) { s = ei[idx]; d = ei[E + idx]; }
  else         { s = d = (int)(idx - E); }
  float v = a_src[s] + a_dst[d];
  v = (v >= 0.f) ? v : NEG_SLOPE * v;
  float w = expf(v);
  int pos = atomicAdd(cursor + d, 1);
  csr[pos] = make_float2(__int_as_float(s), w);
}

// ---------------------------------------------------------------------------
// K5: per-node softmax-normalize + gather-aggregate + relu + W_lin + sigmoid.
// One wave per node; lane = hidden dim; shfl broadcast of (src, w); 4x-unrolled
// independent h-row loads for latency pipelining. No atomics, no LDS.
// ---------------------------------------------------------------------------
__global__ __launch_bounds__(256) void k_gather_final(
    const int* __restrict__ row_start, const int* __restrict__ deg,
    const float2* __restrict__ csr, const float* __restrict__ h,
    const float* __restrict__ bias, const float* __restrict__ W_lin,
    const float* __restrict__ b_lin, float* __restrict__ y, int n)
{
  const int lane = threadIdx.x & 63;
  const int wid  = threadIdx.x >> 6;
  const int node = blockIdx.x * 4 + wid;
  if (node >= n) return;

  const int rs = row_start[node];
  const int dg = deg[node] + 1;          // + self-loop

  // --- pass 1: sum of exp-weights
  float part = 0.f;
  for (int b = 0; b < dg; b += 64) {
    int i = b + lane;
    if (i < dg) part += csr[rs + i].y;
  }
  float ssum = part;
#pragma unroll
  for (int o = 32; o; o >>= 1) ssum += __shfl_xor(ssum, o, 64);
  const float inv = 1.f / ssum;

  // --- pass 2: acc[lane] = sum_e (w_e*inv) * h[src_e][lane]
  float acc = 0.f;
  for (int b = 0; b < dg; b += 64) {
    int i = b + lane;
    float2 pk = (i < dg) ? csr[rs + i] : make_float2(0.f, 0.f);
    int   srcl = __float_as_int(pk.x);
    float wl   = pk.y * inv;
    const int cnt = (dg - b < 64) ? dg - b : 64;

    int j = 0;
    for (; j + 4 <= cnt; j += 4) {
      int   s0 = __shfl(srcl, j,     64), s1 = __shfl(srcl, j + 1, 64);
      int   s2 = __shfl(srcl, j + 2, 64), s3 = __shfl(srcl, j + 3, 64);
      float w0 = __shfl(wl,   j,     64), w1 = __shfl(wl,   j + 1, 64);
      float w2 = __shfl(wl,   j + 2, 64), w3 = __shfl(wl,   j + 3, 64);
      float h0 = h[(size_t)s0 * HID + lane];
      float h1 = h[(size_t)s1 * HID + lane];
      float h2 = h[(size_t)s2 * HID + lane];
      float h3 = h[(size_t)s3 * HID + lane];
      acc = fmaf(w0, h0, acc);
      acc = fmaf(w1, h1, acc);
      acc = fmaf(w2, h2, acc);
      acc = fmaf(w3, h3, acc);
    }
    for (; j < cnt; ++j) {
      int   sj = __shfl(srcl, j, 64);
      float wj = __shfl(wl,   j, 64);
      acc = fmaf(wj, h[(size_t)sj * HID + lane], acc);
    }
  }

  // --- epilogue: relu -> dot W_lin -> sigmoid
  float v = fmaxf(acc + bias[lane], 0.f);
  float z = v * W_lin[lane];
#pragma unroll
  for (int o = 32; o; o >>= 1) z += __shfl_xor(z, o, 64);
  if (lane == 0) {
    z += b_lin[0];
    y[node] = 1.f / (1.f + expf(-z));
  }
}

// ---------------------------------------------------------------------------

extern "C" void kernel_launch(void* const* d_in, const int* in_sizes, int n_in,
                              void* d_out, int out_size, void* d_ws, size_t ws_size,
                              hipStream_t stream)
{
  const float* x     = (const float*)d_in[0];
  const int*   ei    = (const int*)d_in[1];    // [2, E]: row0=src, row1=dst
  const float* W     = (const float*)d_in[2];
  const float* att_s = (const float*)d_in[3];
  const float* att_d = (const float*)d_in[4];
  const float* bias  = (const float*)d_in[5];
  const float* W_lin = (const float*)d_in[6];
  const float* b_lin = (const float*)d_in[7];
  float* y = (float*)d_out;

  const int n = in_sizes[0] / IND;
  const int E = in_sizes[1] / 2;
  const long long E2 = (long long)E + n;
  const int nb = (n + 255) / 256;   // scan blocks (196 for n=50000)

  // Workspace carve-up (~20.5 MB)
  char* ws = (char*)d_ws;
  float*  h       = (float*)ws;  ws += (size_t)n * HID * sizeof(float);
  float*  a_src   = (float*)ws;  ws += (size_t)n * sizeof(float);
  float*  a_dst   = (float*)ws;  ws += (size_t)n * sizeof(float);
  int*    deg     = (int*)ws;    ws += (size_t)n * sizeof(int);
  int*    row_st  = (int*)ws;    ws += (size_t)n * sizeof(int);
  int*    cursor  = (int*)ws;    ws += (size_t)n * sizeof(int);
  int*    bsums   = (int*)ws;    ws += (size_t)1024 * sizeof(int);
  float2* csr     = (float2*)ws; ws += (size_t)E2 * sizeof(float2);

  // d_ws re-poisoned to 0xAA every launch -> re-init each call.
  hipMemsetAsync(deg, 0, (size_t)n * sizeof(int), stream);

  k_hist<<<(E + 255) / 256, 256, 0, stream>>>(ei, deg, E);
  k_scan_a<<<nb, 256, 0, stream>>>(deg, bsums, n);
  k_scan_b<<<1, 1024, 0, stream>>>(bsums, nb);
  k_scan_c<<<nb, 256, 0, stream>>>(deg, bsums, row_st, cursor, n);

  k_proj<<<(n + 63) / 64, 256, 0, stream>>>(x, W, att_s, att_d, h, a_src, a_dst, n);

  k_scatter<<<(int)((E2 + 255) / 256), 256, 0, stream>>>(
      ei, a_src, a_dst, cursor, csr, E, n);

  k_gather_final<<<(n + 3) / 4, 256, 0, stream>>>(
      row_st, deg, csr, h, bias, W_lin, b_lin, y, n);
}